// Round 1
// baseline (101.810 us; speedup 1.0000x reference)
//
#include <hip/hip_runtime.h>
#include <math.h>

#define NB 32
#define NI 1024
#define NJ 2048
#define NC 1024
#define K2 2048   // 2*NI

// ---------------------------------------------------------------------------
// Kernel A: per-batch prep.
//   sim[b,i,j] = r_n[b,i] * h_n[b,j]  (rank-1)  =>
//   pos_map[b,i] = r_n>0 ? r_n*Hpos : r_n*Hneg
//   neg_map[b,i] = r_n>0 ? -r_n*Hneg : -r_n*Hpos
//   with Hpos/Hneg = mean of top/bottom 16 of normalized h row.
// Writes F[b][0:1024]=pos_map, F[b][1024:2048]=neg_map, and
// out[b][c] = bias[c] + token[c]*flag[b]  (kernel B atomicAdds the GEMM).
// ---------------------------------------------------------------------------
__global__ __launch_bounds__(256)
void prep_kernel(const float* __restrict__ f_rad,
                 const float* __restrict__ f_histo,
                 const unsigned char* __restrict__ rad_mask,
                 const unsigned char* __restrict__ histo_mask,
                 const float* __restrict__ bias,
                 const float* __restrict__ token,
                 float* __restrict__ F,
                 float* __restrict__ out)
{
    __shared__ float hb[NJ];          // 8 KB
    __shared__ float lists[256][16];  // 16 KB
    __shared__ float red[256];        // 1 KB
    __shared__ float sc[4];           // hnorm, sumTop, sumTopNeg, rnorm

    const int b = blockIdx.x;
    const int t = threadIdx.x;

    // ---- load h row + sum of squares ----
    float ss = 0.f;
#pragma unroll
    for (int i = 0; i < NJ / 256; ++i) {
        float v = f_histo[b * NJ + t + i * 256];
        hb[t + i * 256] = v;
        ss += v * v;
    }
    red[t] = ss;
    __syncthreads();
#pragma unroll
    for (int s = 128; s > 0; s >>= 1) {
        if (t < s) red[t] += red[t + s];
        __syncthreads();
    }
    if (t == 0) sc[0] = fmaxf(sqrtf(red[0]), 1e-12f);

    // ---- exact top-16 (pass 0) and bottom-16 (pass 1, negated) ----
    for (int pass = 0; pass < 2; ++pass) {
        const float sgn = pass ? -1.f : 1.f;
        float v[16];
#pragma unroll
        for (int i = 0; i < 8; ++i) v[i] = sgn * hb[t + i * 256];
#pragma unroll
        for (int i = 8; i < 16; ++i) v[i] = -__builtin_inff();

        // sort v[0..7] descending — bubble network, compile-time indices
#pragma unroll
        for (int a = 0; a < 7; ++a)
#pragma unroll
            for (int c = 0; c < 7 - a; ++c) {
                float x = v[c], y = v[c + 1];
                v[c] = fmaxf(x, y);
                v[c + 1] = fminf(x, y);
            }

        __syncthreads();   // lists reuse across passes
#pragma unroll
        for (int i = 0; i < 16; ++i) lists[t][i] = v[i];
        __syncthreads();

        // merge tree: 256 sorted-desc-16 lists -> 1 top-16 list
#pragma unroll
        for (int s = 128; s >= 1; s >>= 1) {
            if (t < s) {
                float w[16], m[16];
#pragma unroll
                for (int i = 0; i < 16; ++i) w[i] = lists[t + s][i];
                // bitonic split: top-16 of (A desc ++ B asc), result bitonic
#pragma unroll
                for (int i = 0; i < 16; ++i) m[i] = fmaxf(v[i], w[15 - i]);
                // bitonic cleanup -> descending
#pragma unroll
                for (int st = 8; st >= 1; st >>= 1)
#pragma unroll
                    for (int i = 0; i < 16; ++i)
                        if ((i & st) == 0) {
                            float x = m[i], y = m[i + st];
                            m[i] = fmaxf(x, y);
                            m[i + st] = fminf(x, y);
                        }
#pragma unroll
                for (int i = 0; i < 16; ++i) { v[i] = m[i]; lists[t][i] = m[i]; }
            }
            __syncthreads();
        }
        if (t == 0) {
            float s16 = 0.f;
#pragma unroll
            for (int i = 0; i < 16; ++i) s16 += v[i];
            sc[1 + pass] = s16;
        }
    }

    // ---- f_rad row: norm ----
    float rv[4];
    float ss2 = 0.f;
#pragma unroll
    for (int i = 0; i < 4; ++i) {
        rv[i] = f_rad[b * NI + t + i * 256];
        ss2 += rv[i] * rv[i];
    }
    __syncthreads();
    red[t] = ss2;
    __syncthreads();
#pragma unroll
    for (int s = 128; s > 0; s >>= 1) {
        if (t < s) red[t] += red[t + s];
        __syncthreads();
    }
    if (t == 0) sc[3] = fmaxf(sqrtf(red[0]), 1e-12f);
    __syncthreads();

    const float hnorm = sc[0];
    const float Hpos = sc[1] / (16.f * hnorm);   // mean of top-16 of h_n
    const float Hneg = -sc[2] / (16.f * hnorm);  // mean of bottom-16 of h_n
    const float rnorm = sc[3];

    // ---- write F (feat) ----
#pragma unroll
    for (int i = 0; i < 4; ++i) {
        float rn = rv[i] / rnorm;
        float p, q;
        if (rn > 0.f) { p = rn * Hpos;  q = -rn * Hneg; }
        else          { p = rn * Hneg;  q = -rn * Hpos; }
        F[b * K2 + t + i * 256]      = p;
        F[b * K2 + NI + t + i * 256] = q;
    }

    // ---- out init: bias + token*flag (token == 0 in this problem) ----
    const float flag = (rad_mask[b] != 0 && histo_mask[b] != 0) ? 0.f : 1.f;
#pragma unroll
    for (int i = 0; i < NC / 256; ++i) {
        int c = t + i * 256;
        out[b * NC + c] = bias[c] + token[c] * flag;
    }
}

// ---------------------------------------------------------------------------
// Kernel B: out[b,c] += sum_k F[b,k] * W[c,k]
// grid (128, 2): blockIdx.x = c-tile of 8 (2 c per wave), blockIdx.y = k-half.
// Lanes parallel over k (float4), acc[2][32] in registers, butterfly reduce,
// atomicAdd into pre-initialized out.
// ---------------------------------------------------------------------------
__global__ __launch_bounds__(256)
void gemm_kernel(const float* __restrict__ F,
                 const float* __restrict__ W,
                 float* __restrict__ out)
{
    __shared__ __align__(16) float Fs[NB][512];   // 64 KB

    const int t = threadIdx.x;
    const int k0 = blockIdx.y * 1024;
    const int wave = t >> 6;
    const int lane = t & 63;
    const int c0 = blockIdx.x * 8 + wave * 2;

    float acc0[32], acc1[32];
#pragma unroll
    for (int b = 0; b < 32; ++b) { acc0[b] = 0.f; acc1[b] = 0.f; }

    const float4* Wr0 = reinterpret_cast<const float4*>(W + (size_t)c0 * K2 + k0);
    const float4* Wr1 = reinterpret_cast<const float4*>(W + (size_t)(c0 + 1) * K2 + k0);

    for (int ch = 0; ch < 2; ++ch) {
        const int kbase = k0 + ch * 512;
        // stage F[:, kbase : kbase+512] -> LDS (coalesced float4)
#pragma unroll
        for (int f = 0; f < 16; ++f) {
            int idx = t + f * 256;       // float4 index 0..4095
            int row = idx >> 7;          // /128
            int col = idx & 127;
            reinterpret_cast<float4*>(&Fs[row][0])[col] =
                reinterpret_cast<const float4*>(F + row * K2 + kbase)[col];
        }
        __syncthreads();

#pragma unroll
        for (int r = 0; r < 2; ++r) {
            const int kk4 = r * 64 + lane;         // float4 idx within 512
            float4 w0 = Wr0[ch * 128 + kk4];
            float4 w1 = Wr1[ch * 128 + kk4];
#pragma unroll
            for (int b = 0; b < 32; ++b) {
                float4 fv = reinterpret_cast<const float4*>(&Fs[b][0])[kk4];
                acc0[b] = fmaf(fv.x, w0.x, acc0[b]);
                acc0[b] = fmaf(fv.y, w0.y, acc0[b]);
                acc0[b] = fmaf(fv.z, w0.z, acc0[b]);
                acc0[b] = fmaf(fv.w, w0.w, acc0[b]);
                acc1[b] = fmaf(fv.x, w1.x, acc1[b]);
                acc1[b] = fmaf(fv.y, w1.y, acc1[b]);
                acc1[b] = fmaf(fv.z, w1.z, acc1[b]);
                acc1[b] = fmaf(fv.w, w1.w, acc1[b]);
            }
        }
        __syncthreads();
    }

    // butterfly reduce across the 64 lanes (k direction)
#pragma unroll
    for (int b = 0; b < 32; ++b) {
#pragma unroll
        for (int off = 32; off >= 1; off >>= 1) {
            acc0[b] += __shfl_xor(acc0[b], off, 64);
            acc1[b] += __shfl_xor(acc1[b], off, 64);
        }
    }

    // lane l -> output (b = l>>1, c = c0 + (l&1)); compile-time select
    float myval = 0.f;
    const int bsel = lane >> 1;
    const int csel = lane & 1;
#pragma unroll
    for (int b = 0; b < 32; ++b)
        if (bsel == b) myval = csel ? acc1[b] : acc0[b];

    atomicAdd(&out[bsel * NC + c0 + csel], myval);
}

extern "C" void kernel_launch(void* const* d_in, const int* in_sizes, int n_in,
                              void* d_out, int out_size, void* d_ws, size_t ws_size,
                              hipStream_t stream) {
    const float* f_rad       = (const float*)d_in[0];
    const float* f_histo     = (const float*)d_in[1];
    const unsigned char* rm  = (const unsigned char*)d_in[2];
    const unsigned char* hm  = (const unsigned char*)d_in[3];
    const float* W           = (const float*)d_in[4];
    const float* bias        = (const float*)d_in[5];
    const float* token       = (const float*)d_in[6];
    float* out = (float*)d_out;
    float* F   = (float*)d_ws;   // 32*2048 floats = 256 KB

    prep_kernel<<<NB, 256, 0, stream>>>(f_rad, f_histo, rm, hm, bias, token, F, out);
    dim3 grid(128, 2);
    gemm_kernel<<<grid, 256, 0, stream>>>(F, W, out);
}